// Round 15
// baseline (116.318 us; speedup 1.0000x reference)
//
#include <hip/hip_runtime.h>

#define BSH 7        // col-bin shift: 128 nodes per bin
#define BMSK 127
#define NB 391       // ceil(50000/128)
#define ROWSH 13     // row-chunk shift: 8192 rows (hs window ~2MB, fits XCD L2)
#define NCH 7        // ceil(50000/8192) row chunks
#define NBLKS 128    // phase-A edge blocks (run = E/(NB*NBLKS) = 16 items = 64B sector)
#define BINCAP 3072  // max edges per 128-node bin (avg 2048)
#define HCAP 1792    // max edges per HALF-bin (avg 1024, +24 sigma)
#define SMAX1 768    // staged csr window, fuse2 (16 nodes, avg 272)
#define SMAX2 1024   // staged csr window, gather2 (32 nodes, avg 544)

typedef __attribute__((ext_vector_type(8))) short short8;
typedef __attribute__((ext_vector_type(4))) float f32x4;
typedef __attribute__((ext_vector_type(4))) unsigned int u32x4;

static inline size_t alignup(size_t x) { return (x + 255) & ~(size_t)255; }

__device__ __forceinline__ unsigned short f2bf(float f) {  // RNE fp32->bf16
    unsigned int u = __float_as_uint(f);
    u = (u + 0x7fffu + ((u >> 16) & 1u)) >> 16;
    return (unsigned short)u;
}

// ---- prep: Wt[n][k] = bf16(W[k][n]) (must precede k_front which reads Wt1)
__global__ __launch_bounds__(256) void k_prep(const float* __restrict__ W1,
                                              const float* __restrict__ W2,
                                              unsigned short* __restrict__ Wt1,
                                              unsigned short* __restrict__ Wt2) {
    int i = blockIdx.x * 256 + threadIdx.x;
    if (i < 128 * 128) { int k = i >> 7, c = i & 127; Wt1[(size_t)c * 128 + k] = f2bf(W1[i]); }
    if (i < 128 * 64)  { int k = i >> 6, c = i & 63;  Wt2[(size_t)c * 128 + k] = f2bf(W2[i]); }
}

// ---- FRONT: blocks [0,G1) = gemm1 (hs1 = bf16(x@W1), dependency-free);
//      blocks [G1,G1+NBLKS) = bin-only edge histogram.
__global__ __launch_bounds__(256) void k_front(const float* __restrict__ x,
                                               const unsigned short* __restrict__ Wt1,
                                               unsigned short* __restrict__ hs1, int M,
                                               const int* __restrict__ colp, int nE,
                                               unsigned* __restrict__ counts, int G1) {
    if ((int)blockIdx.x >= G1) {  // ---- histogram path (bin key only)
        int blk = blockIdx.x - G1;
        __shared__ unsigned h[NB];
        for (int i = threadIdx.x; i < NB; i += 256) h[i] = 0;
        __syncthreads();
        int chunk = (nE + NBLKS - 1) / NBLKS;
        int e0 = blk * chunk, e1 = min(nE, e0 + chunk);
        for (int e = e0 + (int)threadIdx.x; e < e1; e += 256)
            atomicAdd(&h[colp[e] >> BSH], 1u);
        __syncthreads();
        for (int i = threadIdx.x; i < NB; i += 256) counts[(size_t)i * NBLKS + blk] = h[i];
        return;
    }
    // ---- gemm1 path (LDS-free MFMA): hs1 = bf16(x @ W1), unscaled
    const int NT = 8;
    const int lane = threadIdx.x & 63;
    const int wave = threadIdx.x >> 6;
    const int m0 = blockIdx.x * 64 + wave * 16;
    const int lrow = lane & 15;
    const int lk = lane >> 4;
    int arow = m0 + lrow;
    if (arow >= M) arow = M - 1;  // clamp; garbage rows never stored

    f32x4 acc[NT];
#pragma unroll
    for (int t = 0; t < NT; ++t) acc[t] = (f32x4){0.f, 0.f, 0.f, 0.f};

#pragma unroll
    for (int k0 = 0; k0 < 4; ++k0) {
        const int kb = k0 * 32 + lk * 8;
        const float* ap = &x[(size_t)arow * 128 + kb];
        f32x4 v0 = __builtin_nontemporal_load((const f32x4*)ap);
        f32x4 v1 = __builtin_nontemporal_load((const f32x4*)(ap + 4));
        short8 afrag;
#pragma unroll
        for (int q = 0; q < 4; ++q) {
            afrag[q] = (short)f2bf(v0[q]);
            afrag[4 + q] = (short)f2bf(v1[q]);
        }
#pragma unroll
        for (int t = 0; t < NT; ++t) {
            const int bcol = t * 16 + lrow;
            short8 bfrag = *(const short8*)&Wt1[(size_t)bcol * 128 + kb];
            acc[t] = __builtin_amdgcn_mfma_f32_16x16x32_bf16(afrag, bfrag, acc[t], 0, 0, 0);
        }
    }
#pragma unroll
    for (int i = 0; i < 4; ++i) {
        int row = m0 + lk * 4 + i;
        if (row < M) {
#pragma unroll
            for (int t = 0; t < NT; ++t)
                hs1[(size_t)row * 128 + t * 16 + lrow] = f2bf(acc[t][i]);
        }
    }
}

// ---- scatter (scanA absorbed): each block reads RAW counts, computes binbase
// (full scan) + its own per-block prefix; block 0 emits edgebase. Runs = 16
// items = 64B sector (dense writes).
__global__ __launch_bounds__(256) void k_scatter(const int* __restrict__ colp,
                                                 const int* __restrict__ rowp, int nE,
                                                 const unsigned* __restrict__ counts,
                                                 unsigned* __restrict__ pairs,
                                                 unsigned* __restrict__ edgebase) {
    __shared__ unsigned bb[NB];
    __shared__ unsigned ts[256];
    int t = threadIdx.x, blk = blockIdx.x;
    const int CH = (NB + 255) / 256;  // 2
    unsigned own[CH], mypre[CH];
    unsigned s = 0;
#pragma unroll
    for (int j = 0; j < CH; ++j) {
        int idx = t * CH + j;
        unsigned tot = 0, pr = 0;
        if (idx < NB) {
            const unsigned* row = &counts[(size_t)idx * NBLKS];
#pragma unroll 4
            for (int b = 0; b < NBLKS; ++b) {
                unsigned v = row[b];
                tot += v;
                pr += (b < blk) ? v : 0u;
            }
        }
        own[j] = s; mypre[j] = pr; s += tot;
    }
    ts[t] = s;
    __syncthreads();
    for (int d = 1; d < 256; d <<= 1) {
        unsigned v = (t >= d) ? ts[t - d] : 0u;
        __syncthreads();
        ts[t] += v;
        __syncthreads();
    }
    unsigned base = ts[t] - s;
#pragma unroll
    for (int j = 0; j < CH; ++j) {
        int idx = t * CH + j;
        if (idx < NB) bb[idx] = base + own[j];  // binbase (block-independent)
    }
    __syncthreads();
    if (blk == 0) {
        for (int b = t; b < NB; b += 256) edgebase[b] = bb[b];
        if (t == 0) edgebase[NB] = (unsigned)nE;
    }
    __syncthreads();
#pragma unroll
    for (int j = 0; j < CH; ++j) {
        int idx = t * CH + j;
        if (idx < NB) bb[idx] += mypre[j];  // this block's cursor start
    }
    __syncthreads();
    int chunk = (nE + NBLKS - 1) / NBLKS;
    int e0 = blk * chunk, e1 = min(nE, e0 + chunk);
    for (int e = e0 + (int)t; e < e1; e += 256) {
        int c = colp[e], r = rowp[e];
        unsigned pos = atomicAdd(&bb[c >> BSH], 1u);
        pairs[pos] = ((unsigned)r << BSH) | (unsigned)(c & BMSK);
    }
}

// ---- binbuild: HALF-bin blocks (2 per bin -> 782 blocks, 2x occupancy).
// Each half-block reads the full bin's pairs, keeps its 64 nodes via register
// stash + block scan (no same-address atomics), chunk-sorts via 448-counter
// hist+scan, writes its contiguous csr segment + off/dis.
__global__ __launch_bounds__(256) void k_binbuild(const unsigned* __restrict__ pairs,
                                                  const unsigned* __restrict__ edgebase,
                                                  unsigned* __restrict__ csr,
                                                  unsigned* __restrict__ off,
                                                  float* __restrict__ dis, int n) {
    __shared__ unsigned lp[HCAP];
    __shared__ unsigned lr[HCAP];
    __shared__ unsigned hist[64 * NCH];  // 448 (node_local, chunk) counters
    __shared__ unsigned scn[256];
    int bh = blockIdx.x, t = threadIdx.x;
    int b = bh >> 1, half = bh & 1;
    unsigned e0 = edgebase[b], e1 = edgebase[b + 1];
    unsigned ec = e1 - e0;
    if (ec > BINCAP) ec = BINCAP;
    for (int i = t; i < 64 * NCH; i += 256) hist[i] = 0;
    __syncthreads();

    // phase 1: strided read, stash my-half items in registers (static indexing)
    unsigned vals[12];
    bool keep[12];
    unsigned nkeep = 0;
#pragma unroll
    for (int j = 0; j < 12; ++j) {
        unsigned i = (unsigned)t + (unsigned)j * 256u;
        bool ok = (i < ec);
        unsigned v = ok ? pairs[e0 + i] : 0u;
        bool kp = ok && (((v >> 6) & 1u) == (unsigned)half);
        vals[j] = v;
        keep[j] = kp;
        if (kp) {
            ++nkeep;
            atomicAdd(&hist[(v & 63u) * NCH + ((v >> BSH) >> ROWSH)], 1u);
        }
    }
    scn[t] = nkeep;
    __syncthreads();
    for (int d = 1; d < 256; d <<= 1) {
        unsigned v = (t >= d) ? scn[t - d] : 0u;
        __syncthreads();
        scn[t] += v;
        __syncthreads();
    }
    unsigned wbase = scn[t] - nkeep;
    unsigned nmine = scn[255];
    if (nmine > HCAP) nmine = HCAP;
    __syncthreads();
#pragma unroll
    for (int j = 0; j < 12; ++j) {
        if (keep[j]) {
            if (wbase < HCAP) lp[wbase] = vals[j];
            ++wbase;
        }
    }

    // phase 2: exclusive scan of hist[448]
    const int HCH = 2;  // 256*2 = 512 >= 448
    unsigned hown[HCH];
    unsigned hs = 0;
#pragma unroll
    for (int j = 0; j < HCH; ++j) {
        int idx = t * HCH + j;
        unsigned v = (idx < 64 * NCH) ? hist[idx] : 0u;
        hown[j] = hs; hs += v;
    }
    scn[t] = hs;
    __syncthreads();
    for (int d = 1; d < 256; d <<= 1) {
        unsigned v = (t >= d) ? scn[t - d] : 0u;
        __syncthreads();
        scn[t] += v;
        __syncthreads();
    }
    unsigned hbase = scn[t] - hs;
    __syncthreads();
#pragma unroll
    for (int j = 0; j < HCH; ++j) {
        int idx = t * HCH + j;
        if (idx < 64 * NCH) hist[idx] = hbase + hown[j];  // exclusive positions
    }
    __syncthreads();

    unsigned cbase = half ? (ec - nmine) : 0u;  // half-0 items precede half-1 in csr
    if (t < 64) {
        int node = (b << BSH) + half * 64 + t;
        if (node < n) {
            unsigned start = hist[t * NCH];
            unsigned next = (t == 63) ? nmine : hist[(t + 1) * NCH];
            off[node] = e0 + cbase + start;
            dis[node] = rsqrtf((float)(next - start + 1));
        }
    }
    if (b == NB - 1 && half == 1 && t == 0) off[n] = e1;  // sentinel = nE
    __syncthreads();

    // phase 3: place into lr by (node, chunk) cursor; write contiguous csr
    for (unsigned i = t; i < nmine; i += 256) {
        unsigned v = lp[i];
        unsigned key = (v & 63u) * NCH + ((v >> BSH) >> ROWSH);
        unsigned pos = atomicAdd(&hist[key], 1u);
        if (pos < HCAP) lr[pos] = v >> BSH;
    }
    __syncthreads();
    for (unsigned i = t; i < nmine; i += 256) csr[e0 + cbase + i] = lr[i];
}

__device__ __forceinline__ void acc8s(float a[8], u32x4 u, float d) {
    a[0] = fmaf(__uint_as_float(u[0] << 16), d, a[0]);
    a[1] = fmaf(__uint_as_float(u[0] & 0xffff0000u), d, a[1]);
    a[2] = fmaf(__uint_as_float(u[1] << 16), d, a[2]);
    a[3] = fmaf(__uint_as_float(u[1] & 0xffff0000u), d, a[3]);
    a[4] = fmaf(__uint_as_float(u[2] << 16), d, a[4]);
    a[5] = fmaf(__uint_as_float(u[2] & 0xffff0000u), d, a[5]);
    a[6] = fmaf(__uint_as_float(u[3] << 16), d, a[6]);
    a[7] = fmaf(__uint_as_float(u[3] & 0xffff0000u), d, a[7]);
}

__device__ __forceinline__ void acc8(float a[8], u32x4 u) {
    a[0] += __uint_as_float(u[0] << 16);
    a[1] += __uint_as_float(u[0] & 0xffff0000u);
    a[2] += __uint_as_float(u[1] << 16);
    a[3] += __uint_as_float(u[1] & 0xffff0000u);
    a[4] += __uint_as_float(u[2] << 16);
    a[5] += __uint_as_float(u[2] & 0xffff0000u);
    a[6] += __uint_as_float(u[3] << 16);
    a[7] += __uint_as_float(u[3] & 0xffff0000u);
}

// ---- FUSED gather1 + bias + relu + GEMM2 (block = 16 nodes = one MFMA row-tile)
__global__ __launch_bounds__(256) void k_fuse2(const unsigned short* __restrict__ hs1,
                                               const unsigned* __restrict__ csr,
                                               const unsigned* __restrict__ off,
                                               const float* __restrict__ dis,
                                               const float* __restrict__ b1,
                                               const unsigned short* __restrict__ Wt2,
                                               unsigned short* __restrict__ hs2, int n) {
    __shared__ unsigned short st[16 * 136];  // 16 rows x 128 bf16, stride 136
    __shared__ unsigned sc_csr[SMAX1];
    __shared__ float sc_dis[SMAX1];
    const int tid = threadIdx.x;
    int vloc = tid >> 4;
    int c = tid & 15;  // 16B chunk (8 bf16)
    int blk16 = blockIdx.x * 16;
    int v = blk16 + vloc;
    if (v >= n) v = n - 1;  // clamp

    unsigned s0 = off[blk16 < n ? blk16 : n - 1];
    unsigned eend = off[(blk16 + 16 < n) ? blk16 + 16 : n];
    unsigned cnt = eend - s0;
    if (cnt > SMAX1) cnt = SMAX1;
    for (unsigned i = tid; i < cnt; i += 256) {
        unsigned r = csr[s0 + i];
        sc_csr[i] = r;
        sc_dis[i] = dis[r];
    }
    __syncthreads();

    const u32x4* h4 = (const u32x4*)hs1;
    size_t base = (size_t)v * 16 + c;
    unsigned ls = off[v] - s0, le = off[v + 1] - s0;
    float dv = dis[v];

    float a[8];
#pragma unroll
    for (int j = 0; j < 8; ++j) a[j] = 0.f;
    acc8s(a, h4[base], dv);  // self-loop: dis[v]*hs1[v]

    if (le <= SMAX1) {  // staged fast path
        unsigned i = ls;
        for (; i + 8 <= le; i += 8) {
            unsigned r[8];
            float d[8];
            u32x4 m[8];
#pragma unroll
            for (int j = 0; j < 8; ++j) { r[j] = sc_csr[i + j]; d[j] = sc_dis[i + j]; }
#pragma unroll
            for (int j = 0; j < 8; ++j) m[j] = h4[(size_t)r[j] * 16 + c];
#pragma unroll
            for (int j = 0; j < 8; ++j) acc8s(a, m[j], d[j]);
        }
        for (; i < le; ++i)
            acc8s(a, h4[(size_t)sc_csr[i] * 16 + c], sc_dis[i]);
    } else {  // global fallback (never in practice)
        for (unsigned i = ls; i < le; ++i) {
            unsigned r = csr[s0 + i];
            acc8s(a, h4[(size_t)r * 16 + c], dis[r]);
        }
    }

    u32x4 pk;
#pragma unroll
    for (int q = 0; q < 4; ++q) {
        float lo = fmaxf(a[2 * q] * dv + b1[c * 8 + 2 * q], 0.f);
        float hi = fmaxf(a[2 * q + 1] * dv + b1[c * 8 + 2 * q + 1], 0.f);
        pk[q] = (unsigned)f2bf(lo) | ((unsigned)f2bf(hi) << 16);
    }
    *(u32x4*)&st[vloc * 136 + c * 8] = pk;
    __syncthreads();

    const int lane = tid & 63;
    const int wave = tid >> 6;
    const int lrow = lane & 15;
    const int lk = lane >> 4;
    f32x4 acc = (f32x4){0.f, 0.f, 0.f, 0.f};
#pragma unroll
    for (int k0 = 0; k0 < 4; ++k0) {
        const int kb = k0 * 32 + lk * 8;
        short8 afrag = *(const short8*)&st[lrow * 136 + kb];
        const int bcol = wave * 16 + lrow;
        short8 bfrag = *(const short8*)&Wt2[(size_t)bcol * 128 + kb];
        acc = __builtin_amdgcn_mfma_f32_16x16x32_bf16(afrag, bfrag, acc, 0, 0, 0);
    }
#pragma unroll
    for (int i2 = 0; i2 < 4; ++i2) {
        int row = blk16 + lk * 4 + i2;
        if (row < n) {
            float sc = dis[row];
            hs2[(size_t)row * 64 + wave * 16 + lrow] = f2bf(acc[i2] * sc);  // pre-scaled
        }
    }
}

// ---- gather2 over pre-scaled hs2 (csr staged in LDS): out = dis*(self+sum) + b2
__global__ __launch_bounds__(256) void k_gather2(const unsigned short* __restrict__ hs,
                                                 const unsigned* __restrict__ csr,
                                                 const unsigned* __restrict__ off,
                                                 const float* __restrict__ dis,
                                                 const float* __restrict__ bias,
                                                 float* __restrict__ outp, int n) {
    __shared__ unsigned sc_csr[SMAX2];
    const int tid = threadIdx.x;
    int blk32 = blockIdx.x * 32;
    int v = blk32 + (tid >> 3);
    int c = tid & 7;
    bool live = (v < n);
    if (!live) v = n - 1;

    unsigned s0 = off[blk32 < n ? blk32 : n - 1];
    unsigned eend = off[(blk32 + 32 < n) ? blk32 + 32 : n];
    unsigned cnt = eend - s0;
    if (cnt > SMAX2) cnt = SMAX2;
    for (unsigned i = tid; i < cnt; i += 256) sc_csr[i] = csr[s0 + i];
    __syncthreads();
    if (!live) return;

    const u32x4* h4 = (const u32x4*)hs;
    size_t base = (size_t)v * 8 + c;
    unsigned ls = off[v] - s0, le = off[v + 1] - s0;
    float dv = dis[v];

    float a[8];
#pragma unroll
    for (int j = 0; j < 8; ++j) a[j] = 0.f;
    acc8(a, h4[base]);  // self-loop (pre-scaled)

    if (le <= SMAX2) {  // staged fast path
        unsigned i = ls;
        for (; i + 8 <= le; i += 8) {
            unsigned r[8];
            u32x4 m[8];
#pragma unroll
            for (int j = 0; j < 8; ++j) r[j] = sc_csr[i + j];
#pragma unroll
            for (int j = 0; j < 8; ++j) m[j] = h4[(size_t)r[j] * 8 + c];
#pragma unroll
            for (int j = 0; j < 8; ++j) acc8(a, m[j]);
        }
        for (; i < le; ++i) acc8(a, h4[(size_t)sc_csr[i] * 8 + c]);
    } else {  // global fallback
        for (unsigned i = ls; i < le; ++i) acc8(a, h4[(size_t)csr[s0 + i] * 8 + c]);
    }

    float rr[8];
#pragma unroll
    for (int j = 0; j < 8; ++j) rr[j] = a[j] * dv + bias[c * 8 + j];
    f32x4 lov = {rr[0], rr[1], rr[2], rr[3]};
    f32x4 hiv = {rr[4], rr[5], rr[6], rr[7]};
    __builtin_nontemporal_store(lov, (f32x4*)&outp[(size_t)v * 64 + c * 8]);
    __builtin_nontemporal_store(hiv, (f32x4*)&outp[(size_t)v * 64 + c * 8 + 4]);
}

extern "C" void kernel_launch(void* const* d_in, const int* in_sizes, int n_in,
                              void* d_out, int out_size, void* d_ws, size_t ws_size,
                              hipStream_t stream) {
    const float* x  = (const float*)d_in[0];
    const int*   ei = (const int*)d_in[1];
    const float* W1 = (const float*)d_in[2];
    const float* b1 = (const float*)d_in[3];
    const float* W2 = (const float*)d_in[4];
    const float* b2 = (const float*)d_in[5];

    const int Din = 128;
    const int Nn = in_sizes[0] / Din;   // 50000
    const int E  = in_sizes[1] / 2;     // 800000
    const int* rowp = ei;
    const int* colp = ei + E;

    char* ws = (char*)d_ws;
    size_t off_ = 0;
    unsigned*       counts   = (unsigned*)(ws + off_);       off_ = alignup(off_ + (size_t)NB * NBLKS * 4);
    unsigned*       edgebase = (unsigned*)(ws + off_);       off_ = alignup(off_ + (size_t)(NB + 1) * 4);
    unsigned*       pairs    = (unsigned*)(ws + off_);       off_ = alignup(off_ + (size_t)E * 4);
    unsigned*       csr      = (unsigned*)(ws + off_);       off_ = alignup(off_ + (size_t)E * 4);
    unsigned*       offv     = (unsigned*)(ws + off_);       off_ = alignup(off_ + (size_t)(Nn + 1) * 4);
    float*          dis      = (float*)(ws + off_);          off_ = alignup(off_ + (size_t)Nn * 4);
    unsigned short* Wt1      = (unsigned short*)(ws + off_); off_ = alignup(off_ + 128 * 128 * 2);
    unsigned short* Wt2      = (unsigned short*)(ws + off_); off_ = alignup(off_ + 128 * 64 * 2);
    unsigned short* hs1      = (unsigned short*)(ws + off_); off_ = alignup(off_ + (size_t)Nn * 128 * 2);
    unsigned short* hs2      = (unsigned short*)(ws + off_); off_ = alignup(off_ + (size_t)Nn * 64 * 2);
    float*          outp     = (float*)d_out;

    const int G1 = (Nn + 63) / 64;  // 782 gemm1 blocks

    // prep -> (gemm1 || hist) -> scatter(+scan) -> half-bin binbuild
    k_prep<<<64, 256, 0, stream>>>(W1, W2, Wt1, Wt2);
    k_front<<<G1 + NBLKS, 256, 0, stream>>>(x, Wt1, hs1, Nn, colp, E, counts, G1);
    k_scatter<<<NBLKS, 256, 0, stream>>>(colp, rowp, E, counts, pairs, edgebase);
    k_binbuild<<<2 * NB, 256, 0, stream>>>(pairs, edgebase, csr, offv, dis, Nn);

    // fused: gather1(staged csr+dis) + b1 + relu + GEMM2 -> hs2 (pre-scaled)
    k_fuse2<<<(Nn + 15) / 16, 256, 0, stream>>>(hs1, csr, offv, dis, b1, Wt2, hs2, Nn);

    // out = dis[v] * (hs2[v] + sum hs2[r]) + b2   (fp32, staged csr)
    k_gather2<<<(Nn + 31) / 32, 256, 0, stream>>>(hs2, csr, offv, dis, b2, outp, Nn);
}

// Round 16
// 110.408 us; speedup vs baseline: 1.0535x; 1.0535x over previous
//
#include <hip/hip_runtime.h>

#define BSH 7        // col-bin shift: 128 nodes per bin
#define BMSK 127
#define NB 391       // ceil(50000/128)
#define ROWSH 13     // row-chunk shift: 8192 rows (hs window ~2MB, fits XCD L2)
#define NCH 7        // ceil(50000/8192) row chunks
#define NBLKS 128    // phase-A edge blocks (run = E/(NB*NBLKS) = 16 items = 64B sector)
#define BINCAP 3072  // max edges per 128-node bin (avg 2048)
#define SMAX1 768    // staged csr window, fuse2 (16 nodes, avg 272, P(>768)~e-300)
#define SMAX2 1024   // staged csr window, gather2 (32 nodes, avg 544)

typedef __attribute__((ext_vector_type(8))) short short8;
typedef __attribute__((ext_vector_type(4))) float f32x4;
typedef __attribute__((ext_vector_type(4))) unsigned int u32x4;

static inline size_t alignup(size_t x) { return (x + 255) & ~(size_t)255; }

__device__ __forceinline__ unsigned short f2bf(float f) {  // RNE fp32->bf16
    unsigned int u = __float_as_uint(f);
    u = (u + 0x7fffu + ((u >> 16) & 1u)) >> 16;
    return (unsigned short)u;
}

// ---- prep: Wt[n][k] = bf16(W[k][n]) (must precede k_front which reads Wt1)
__global__ __launch_bounds__(256) void k_prep(const float* __restrict__ W1,
                                              const float* __restrict__ W2,
                                              unsigned short* __restrict__ Wt1,
                                              unsigned short* __restrict__ Wt2) {
    int i = blockIdx.x * 256 + threadIdx.x;
    if (i < 128 * 128) { int k = i >> 7, c = i & 127; Wt1[(size_t)c * 128 + k] = f2bf(W1[i]); }
    if (i < 128 * 64)  { int k = i >> 6, c = i & 63;  Wt2[(size_t)c * 128 + k] = f2bf(W2[i]); }
}

// ---- FRONT: blocks [0,G1) = gemm1 (hs1 = bf16(x@W1), dependency-free);
//      blocks [G1,G1+NBLKS) = bin-only edge histogram (dense streams both ways).
__global__ __launch_bounds__(256) void k_front(const float* __restrict__ x,
                                               const unsigned short* __restrict__ Wt1,
                                               unsigned short* __restrict__ hs1, int M,
                                               const int* __restrict__ colp, int nE,
                                               unsigned* __restrict__ counts, int G1) {
    if ((int)blockIdx.x >= G1) {  // ---- histogram path (bin key only)
        int blk = blockIdx.x - G1;
        __shared__ unsigned h[NB];
        for (int i = threadIdx.x; i < NB; i += 256) h[i] = 0;
        __syncthreads();
        int chunk = (nE + NBLKS - 1) / NBLKS;
        int e0 = blk * chunk, e1 = min(nE, e0 + chunk);
        for (int e = e0 + (int)threadIdx.x; e < e1; e += 256)
            atomicAdd(&h[colp[e] >> BSH], 1u);
        __syncthreads();
        for (int i = threadIdx.x; i < NB; i += 256) counts[(size_t)i * NBLKS + blk] = h[i];
        return;
    }
    // ---- gemm1 path (LDS-free MFMA): hs1 = bf16(x @ W1), unscaled
    const int NT = 8;
    const int lane = threadIdx.x & 63;
    const int wave = threadIdx.x >> 6;
    const int m0 = blockIdx.x * 64 + wave * 16;
    const int lrow = lane & 15;
    const int lk = lane >> 4;
    int arow = m0 + lrow;
    if (arow >= M) arow = M - 1;  // clamp; garbage rows never stored

    f32x4 acc[NT];
#pragma unroll
    for (int t = 0; t < NT; ++t) acc[t] = (f32x4){0.f, 0.f, 0.f, 0.f};

#pragma unroll
    for (int k0 = 0; k0 < 4; ++k0) {
        const int kb = k0 * 32 + lk * 8;
        const float* ap = &x[(size_t)arow * 128 + kb];
        f32x4 v0 = __builtin_nontemporal_load((const f32x4*)ap);
        f32x4 v1 = __builtin_nontemporal_load((const f32x4*)(ap + 4));
        short8 afrag;
#pragma unroll
        for (int q = 0; q < 4; ++q) {
            afrag[q] = (short)f2bf(v0[q]);
            afrag[4 + q] = (short)f2bf(v1[q]);
        }
#pragma unroll
        for (int t = 0; t < NT; ++t) {
            const int bcol = t * 16 + lrow;
            short8 bfrag = *(const short8*)&Wt1[(size_t)bcol * 128 + kb];
            acc[t] = __builtin_amdgcn_mfma_f32_16x16x32_bf16(afrag, bfrag, acc[t], 0, 0, 0);
        }
    }
#pragma unroll
    for (int i = 0; i < 4; ++i) {
        int row = m0 + lk * 4 + i;
        if (row < M) {
#pragma unroll
            for (int t = 0; t < NT; ++t)
                hs1[(size_t)row * 128 + t * 16 + lrow] = f2bf(acc[t][i]);
        }
    }
}

// ---- scanA: per-bin exclusive scan of NBLKS per-block counts (in place); bintot
__global__ __launch_bounds__(NBLKS) void k_scanA(unsigned* __restrict__ counts,
                                                 unsigned* __restrict__ bintot) {
    int bin = blockIdx.x, t = threadIdx.x;
    __shared__ unsigned ps[NBLKS];
    unsigned s = counts[(size_t)bin * NBLKS + t];
    ps[t] = s;
    __syncthreads();
    for (int d = 1; d < NBLKS; d <<= 1) {
        unsigned v = (t >= d) ? ps[t - d] : 0u;
        __syncthreads();
        ps[t] += v;
        __syncthreads();
    }
    counts[(size_t)bin * NBLKS + t] = ps[t] - s;  // exclusive
    if (t == NBLKS - 1) bintot[bin] = ps[NBLKS - 1];
}

// ---- scatter: bin-key positions; each block scans bintot (391) in LDS for
// binbase (replaces scanB; block 0 emits edgebase); runs of ~16 items = 64B.
__global__ __launch_bounds__(256) void k_scatter(const int* __restrict__ colp,
                                                 const int* __restrict__ rowp, int nE,
                                                 const unsigned* __restrict__ counts,
                                                 const unsigned* __restrict__ bintot,
                                                 unsigned* __restrict__ pairs,
                                                 unsigned* __restrict__ edgebase) {
    __shared__ unsigned bb[NB];   // bintot -> binbase -> per-block cursors
    __shared__ unsigned ts[256];
    int t = threadIdx.x, blk = blockIdx.x;
    for (int i = t; i < NB; i += 256) bb[i] = bintot[i];
    __syncthreads();
    const int CH = (NB + 255) / 256;  // 2
    unsigned s = 0;
    unsigned own[CH];
#pragma unroll
    for (int j = 0; j < CH; ++j) {
        int idx = t * CH + j;
        unsigned v = (idx < NB) ? bb[idx] : 0u;
        own[j] = s; s += v;
    }
    ts[t] = s;
    __syncthreads();
    for (int d = 1; d < 256; d <<= 1) {
        unsigned v = (t >= d) ? ts[t - d] : 0u;
        __syncthreads();
        ts[t] += v;
        __syncthreads();
    }
    unsigned base = ts[t] - s;
    __syncthreads();
#pragma unroll
    for (int j = 0; j < CH; ++j) {
        int idx = t * CH + j;
        if (idx < NB) bb[idx] = base + own[j];  // binbase
    }
    __syncthreads();
    if (blk == 0) {
        for (int b = t; b < NB; b += 256) edgebase[b] = bb[b];
        if (t == 0) edgebase[NB] = (unsigned)nE;
    }
    for (int i = t; i < NB; i += 256) bb[i] += counts[(size_t)i * NBLKS + blk];
    __syncthreads();
    int chunk = (nE + NBLKS - 1) / NBLKS;
    int e0 = blk * chunk, e1 = min(nE, e0 + chunk);
    for (int e = e0 + (int)t; e < e1; e += 256) {
        int c = colp[e], r = rowp[e];
        unsigned pos = atomicAdd(&bb[c >> BSH], 1u);
        pairs[pos] = ((unsigned)r << BSH) | (unsigned)(c & BMSK);
    }
}

// ---- binbuild: per-bin CSR in LDS with EXACT (node, row-chunk) two-level sort
__global__ __launch_bounds__(256) void k_binbuild(const unsigned* __restrict__ pairs,
                                                  const unsigned* __restrict__ edgebase,
                                                  unsigned* __restrict__ csr,
                                                  unsigned* __restrict__ off,
                                                  float* __restrict__ dis, int n) {
    __shared__ unsigned lp[BINCAP];
    __shared__ unsigned lr[BINCAP];
    __shared__ unsigned hist[128 * NCH];  // 896 (node, chunk) counters
    __shared__ unsigned scn[256];
    int b = blockIdx.x, t = threadIdx.x;
    unsigned e0 = edgebase[b], e1 = edgebase[b + 1];
    unsigned ec = e1 - e0;
    if (ec > BINCAP) ec = BINCAP;
    for (int i = t; i < 128 * NCH; i += 256) hist[i] = 0;
    __syncthreads();
    for (unsigned i = t; i < ec; i += 256) {
        unsigned v = pairs[e0 + i];
        lp[i] = v;
        unsigned key = (v & BMSK) * NCH + ((v >> BSH) >> ROWSH);
        atomicAdd(&hist[key], 1u);
    }
    __syncthreads();
    const int HCH = 4;  // 256*4 = 1024 >= 896
    unsigned own[HCH];
    unsigned s = 0;
#pragma unroll
    for (int j = 0; j < HCH; ++j) {
        int idx = t * HCH + j;
        unsigned v = (idx < 128 * NCH) ? hist[idx] : 0u;
        own[j] = s; s += v;
    }
    scn[t] = s;
    __syncthreads();
    for (int d = 1; d < 256; d <<= 1) {
        unsigned v = (t >= d) ? scn[t - d] : 0u;
        __syncthreads();
        scn[t] += v;
        __syncthreads();
    }
    unsigned base = scn[t] - s;
    __syncthreads();
#pragma unroll
    for (int j = 0; j < HCH; ++j) {
        int idx = t * HCH + j;
        if (idx < 128 * NCH) hist[idx] = base + own[j];  // exclusive positions
    }
    __syncthreads();
    if (t < 128) {
        int node = (b << BSH) + t;
        if (node < n) {
            unsigned start = hist[t * NCH];
            unsigned next = (t == 127) ? ec : hist[(t + 1) * NCH];
            off[node] = e0 + start;
            dis[node] = rsqrtf((float)(next - start + 1));
        }
    }
    if (b == NB - 1 && t == 0) off[n] = e1;  // sentinel = nE
    __syncthreads();
    for (unsigned i = t; i < ec; i += 256) {
        unsigned v = lp[i];
        unsigned key = (v & BMSK) * NCH + ((v >> BSH) >> ROWSH);
        unsigned pos = atomicAdd(&hist[key], 1u);
        lr[pos] = v >> BSH;
    }
    __syncthreads();
    for (unsigned i = t; i < ec; i += 256) csr[e0 + i] = lr[i];
}

__device__ __forceinline__ void acc8s(float a[8], u32x4 u, float d) {
    a[0] = fmaf(__uint_as_float(u[0] << 16), d, a[0]);
    a[1] = fmaf(__uint_as_float(u[0] & 0xffff0000u), d, a[1]);
    a[2] = fmaf(__uint_as_float(u[1] << 16), d, a[2]);
    a[3] = fmaf(__uint_as_float(u[1] & 0xffff0000u), d, a[3]);
    a[4] = fmaf(__uint_as_float(u[2] << 16), d, a[4]);
    a[5] = fmaf(__uint_as_float(u[2] & 0xffff0000u), d, a[5]);
    a[6] = fmaf(__uint_as_float(u[3] << 16), d, a[6]);
    a[7] = fmaf(__uint_as_float(u[3] & 0xffff0000u), d, a[7]);
}

__device__ __forceinline__ void acc8(float a[8], u32x4 u) {
    a[0] += __uint_as_float(u[0] << 16);
    a[1] += __uint_as_float(u[0] & 0xffff0000u);
    a[2] += __uint_as_float(u[1] << 16);
    a[3] += __uint_as_float(u[1] & 0xffff0000u);
    a[4] += __uint_as_float(u[2] << 16);
    a[5] += __uint_as_float(u[2] & 0xffff0000u);
    a[6] += __uint_as_float(u[3] << 16);
    a[7] += __uint_as_float(u[3] & 0xffff0000u);
}

// ---- FUSED gather1 + bias + relu + GEMM2 (block = 16 nodes = one MFMA row-tile)
// The block's 16 contiguous nodes own ONE contiguous csr segment: stage csr+dis
// in LDS (one coalesced pass) so the hot loop issues only the useful 16B hs
// loads. Global fallback if a node's range exceeds the staged window.
__global__ __launch_bounds__(256) void k_fuse2(const unsigned short* __restrict__ hs1,
                                               const unsigned* __restrict__ csr,
                                               const unsigned* __restrict__ off,
                                               const float* __restrict__ dis,
                                               const float* __restrict__ b1,
                                               const unsigned short* __restrict__ Wt2,
                                               unsigned short* __restrict__ hs2, int n) {
    __shared__ unsigned short st[16 * 136];  // 16 rows x 128 bf16, stride 136
    __shared__ unsigned sc_csr[SMAX1];
    __shared__ float sc_dis[SMAX1];
    const int tid = threadIdx.x;
    int vloc = tid >> 4;
    int c = tid & 15;  // 16B chunk (8 bf16)
    int blk16 = blockIdx.x * 16;
    int v = blk16 + vloc;
    if (v >= n) v = n - 1;  // clamp

    // stage this block's adjacency slice
    unsigned s0 = off[blk16 < n ? blk16 : n - 1];
    unsigned eend = off[(blk16 + 16 < n) ? blk16 + 16 : n];
    unsigned cnt = eend - s0;
    if (cnt > SMAX1) cnt = SMAX1;
    for (unsigned i = tid; i < cnt; i += 256) {
        unsigned r = csr[s0 + i];
        sc_csr[i] = r;
        sc_dis[i] = dis[r];
    }
    __syncthreads();

    const u32x4* h4 = (const u32x4*)hs1;
    size_t base = (size_t)v * 16 + c;
    unsigned ls = off[v] - s0, le = off[v + 1] - s0;
    float dv = dis[v];

    float a[8];
#pragma unroll
    for (int j = 0; j < 8; ++j) a[j] = 0.f;
    acc8s(a, h4[base], dv);  // self-loop: dis[v]*hs1[v]

    if (le <= SMAX1) {  // staged fast path
        unsigned i = ls;
        for (; i + 8 <= le; i += 8) {
            unsigned r[8];
            float d[8];
            u32x4 m[8];
#pragma unroll
            for (int j = 0; j < 8; ++j) { r[j] = sc_csr[i + j]; d[j] = sc_dis[i + j]; }
#pragma unroll
            for (int j = 0; j < 8; ++j) m[j] = h4[(size_t)r[j] * 16 + c];
#pragma unroll
            for (int j = 0; j < 8; ++j) acc8s(a, m[j], d[j]);
        }
        for (; i < le; ++i)
            acc8s(a, h4[(size_t)sc_csr[i] * 16 + c], sc_dis[i]);
    } else {  // global fallback (never in practice)
        for (unsigned i = ls; i < le; ++i) {
            unsigned r = csr[s0 + i];
            acc8s(a, h4[(size_t)r * 16 + c], dis[r]);
        }
    }

    u32x4 pk;
#pragma unroll
    for (int q = 0; q < 4; ++q) {
        float lo = fmaxf(a[2 * q] * dv + b1[c * 8 + 2 * q], 0.f);
        float hi = fmaxf(a[2 * q + 1] * dv + b1[c * 8 + 2 * q + 1], 0.f);
        pk[q] = (unsigned)f2bf(lo) | ((unsigned)f2bf(hi) << 16);
    }
    *(u32x4*)&st[vloc * 136 + c * 8] = pk;
    __syncthreads();

    const int lane = tid & 63;
    const int wave = tid >> 6;
    const int lrow = lane & 15;
    const int lk = lane >> 4;
    f32x4 acc = (f32x4){0.f, 0.f, 0.f, 0.f};
#pragma unroll
    for (int k0 = 0; k0 < 4; ++k0) {
        const int kb = k0 * 32 + lk * 8;
        short8 afrag = *(const short8*)&st[lrow * 136 + kb];
        const int bcol = wave * 16 + lrow;
        short8 bfrag = *(const short8*)&Wt2[(size_t)bcol * 128 + kb];
        acc = __builtin_amdgcn_mfma_f32_16x16x32_bf16(afrag, bfrag, acc, 0, 0, 0);
    }
#pragma unroll
    for (int i2 = 0; i2 < 4; ++i2) {
        int row = blk16 + lk * 4 + i2;
        if (row < n) {
            float sc = dis[row];
            hs2[(size_t)row * 64 + wave * 16 + lrow] = f2bf(acc[i2] * sc);  // pre-scaled
        }
    }
}

// ---- gather2 over pre-scaled hs2 (csr staged in LDS): out = dis*(self+sum) + b2
__global__ __launch_bounds__(256) void k_gather2(const unsigned short* __restrict__ hs,
                                                 const unsigned* __restrict__ csr,
                                                 const unsigned* __restrict__ off,
                                                 const float* __restrict__ dis,
                                                 const float* __restrict__ bias,
                                                 float* __restrict__ outp, int n) {
    __shared__ unsigned sc_csr[SMAX2];
    const int tid = threadIdx.x;
    int blk32 = blockIdx.x * 32;
    int v = blk32 + (tid >> 3);
    int c = tid & 7;
    bool live = (v < n);
    if (!live) v = n - 1;

    unsigned s0 = off[blk32 < n ? blk32 : n - 1];
    unsigned eend = off[(blk32 + 32 < n) ? blk32 + 32 : n];
    unsigned cnt = eend - s0;
    if (cnt > SMAX2) cnt = SMAX2;
    for (unsigned i = tid; i < cnt; i += 256) sc_csr[i] = csr[s0 + i];
    __syncthreads();
    if (!live) return;

    const u32x4* h4 = (const u32x4*)hs;
    size_t base = (size_t)v * 8 + c;
    unsigned ls = off[v] - s0, le = off[v + 1] - s0;
    float dv = dis[v];

    float a[8];
#pragma unroll
    for (int j = 0; j < 8; ++j) a[j] = 0.f;
    acc8(a, h4[base]);  // self-loop (pre-scaled)

    if (le <= SMAX2) {  // staged fast path
        unsigned i = ls;
        for (; i + 8 <= le; i += 8) {
            unsigned r[8];
            u32x4 m[8];
#pragma unroll
            for (int j = 0; j < 8; ++j) r[j] = sc_csr[i + j];
#pragma unroll
            for (int j = 0; j < 8; ++j) m[j] = h4[(size_t)r[j] * 8 + c];
#pragma unroll
            for (int j = 0; j < 8; ++j) acc8(a, m[j]);
        }
        for (; i < le; ++i) acc8(a, h4[(size_t)sc_csr[i] * 8 + c]);
    } else {  // global fallback
        for (unsigned i = ls; i < le; ++i) acc8(a, h4[(size_t)csr[s0 + i] * 8 + c]);
    }

    float rr[8];
#pragma unroll
    for (int j = 0; j < 8; ++j) rr[j] = a[j] * dv + bias[c * 8 + j];
    f32x4 lov = {rr[0], rr[1], rr[2], rr[3]};
    f32x4 hiv = {rr[4], rr[5], rr[6], rr[7]};
    __builtin_nontemporal_store(lov, (f32x4*)&outp[(size_t)v * 64 + c * 8]);
    __builtin_nontemporal_store(hiv, (f32x4*)&outp[(size_t)v * 64 + c * 8 + 4]);
}

extern "C" void kernel_launch(void* const* d_in, const int* in_sizes, int n_in,
                              void* d_out, int out_size, void* d_ws, size_t ws_size,
                              hipStream_t stream) {
    const float* x  = (const float*)d_in[0];
    const int*   ei = (const int*)d_in[1];
    const float* W1 = (const float*)d_in[2];
    const float* b1 = (const float*)d_in[3];
    const float* W2 = (const float*)d_in[4];
    const float* b2 = (const float*)d_in[5];

    const int Din = 128;
    const int Nn = in_sizes[0] / Din;   // 50000
    const int E  = in_sizes[1] / 2;     // 800000
    const int* rowp = ei;
    const int* colp = ei + E;

    char* ws = (char*)d_ws;
    size_t off_ = 0;
    unsigned*       counts   = (unsigned*)(ws + off_);       off_ = alignup(off_ + (size_t)NB * NBLKS * 4);
    unsigned*       bintot   = (unsigned*)(ws + off_);       off_ = alignup(off_ + (size_t)NB * 4);
    unsigned*       edgebase = (unsigned*)(ws + off_);       off_ = alignup(off_ + (size_t)(NB + 1) * 4);
    unsigned*       pairs    = (unsigned*)(ws + off_);       off_ = alignup(off_ + (size_t)E * 4);
    unsigned*       csr      = (unsigned*)(ws + off_);       off_ = alignup(off_ + (size_t)E * 4);
    unsigned*       offv     = (unsigned*)(ws + off_);       off_ = alignup(off_ + (size_t)(Nn + 1) * 4);
    float*          dis      = (float*)(ws + off_);          off_ = alignup(off_ + (size_t)Nn * 4);
    unsigned short* Wt1      = (unsigned short*)(ws + off_); off_ = alignup(off_ + 128 * 128 * 2);
    unsigned short* Wt2      = (unsigned short*)(ws + off_); off_ = alignup(off_ + 128 * 64 * 2);
    unsigned short* hs1      = (unsigned short*)(ws + off_); off_ = alignup(off_ + (size_t)Nn * 128 * 2);
    unsigned short* hs2      = (unsigned short*)(ws + off_); off_ = alignup(off_ + (size_t)Nn * 64 * 2);
    float*          outp     = (float*)d_out;

    const int G1 = (Nn + 63) / 64;  // 782 gemm1 blocks

    // prep -> (gemm1 || hist) -> scanA -> scatter(+binbase scan) -> binbuild
    k_prep<<<64, 256, 0, stream>>>(W1, W2, Wt1, Wt2);
    k_front<<<G1 + NBLKS, 256, 0, stream>>>(x, Wt1, hs1, Nn, colp, E, counts, G1);
    k_scanA<<<NB, NBLKS, 0, stream>>>(counts, bintot);
    k_scatter<<<NBLKS, 256, 0, stream>>>(colp, rowp, E, counts, bintot, pairs, edgebase);
    k_binbuild<<<NB, 256, 0, stream>>>(pairs, edgebase, csr, offv, dis, Nn);

    // fused: gather1(staged csr+dis) + b1 + relu + GEMM2 -> hs2 (pre-scaled)
    k_fuse2<<<(Nn + 15) / 16, 256, 0, stream>>>(hs1, csr, offv, dis, b1, Wt2, hs2, Nn);

    // out = dis[v] * (hs2[v] + sum hs2[r]) + b2   (fp32, staged csr)
    k_gather2<<<(Nn + 31) / 32, 256, 0, stream>>>(hs2, csr, offv, dis, b2, outp, Nn);
}